// Round 6
// baseline (359.004 us; speedup 1.0000x reference)
//
#include <hip/hip_runtime.h>
#include <hip/hip_bf16.h>

#define BSz 2
#define Nn 15135
#define Ee 242160
#define F_INc 8
#define Hh 64
#define Ll 4
#define HFCc 256
#define NCc 10
#define EPSg 1e-15f
#define NBLK ((Nn + 255) / 256)   // 60 scan blocks

__device__ __forceinline__ float uf(unsigned u) { return __uint_as_float(u); }
__device__ __forceinline__ unsigned short bs16(float f) {
    unsigned b = __float_as_uint(f);
    return (unsigned short)((b + 0x7FFFu + ((b >> 16) & 1u)) >> 16);
}
__device__ __forceinline__ unsigned packbf(float a, float b) {
    return (unsigned)bs16(a) | ((unsigned)bs16(b) << 16);
}

// ---- CSR build ----------------------------------------------------------

__global__ void count_kernel(const int* __restrict__ dst, int* __restrict__ cnt) {
    int e = blockIdx.x * blockDim.x + threadIdx.x;
    if (e < Ee) atomicAdd(&cnt[dst[e]], 1);
}

__global__ void scan_local(const int* __restrict__ cnt, int* __restrict__ loc,
                           int* __restrict__ bsum) {
    int tid = threadIdx.x, lane = tid & 63, w = tid >> 6;
    int i = blockIdx.x * 256 + tid;
    __shared__ int ws[4];
    int v = (i < Nn) ? cnt[i] : 0;
    int incl = v;
#pragma unroll
    for (int d = 1; d < 64; d <<= 1) {
        int t = __shfl_up(incl, d, 64);
        if (lane >= d) incl += t;
    }
    if (lane == 63) ws[w] = incl;
    __syncthreads();
    int pre = 0;
    for (int ww = 0; ww < w; ++ww) pre += ws[ww];
    if (i < Nn) loc[i] = pre + incl - v;
    if (tid == 255) bsum[blockIdx.x] = pre + incl;
}

__global__ void scan_tops(int* __restrict__ bsum) {
    int lane = threadIdx.x;
    int v = (lane < NBLK) ? bsum[lane] : 0;
    int incl = v;
#pragma unroll
    for (int d = 1; d < 64; d <<= 1) {
        int t = __shfl_up(incl, d, 64);
        if (lane >= d) incl += t;
    }
    if (lane < NBLK) bsum[lane] = incl - v;
}

__global__ void scan_fix(const int* __restrict__ loc, const int* __restrict__ bsum,
                         int* __restrict__ offs, int* __restrict__ cursor) {
    int i = blockIdx.x * 256 + threadIdx.x;
    if (i < Nn) {
        int o = loc[i] + bsum[blockIdx.x];
        offs[i] = o;
        cursor[i] = o;
    }
    if (i == 0) offs[Nn] = Ee;
}

// fill CSR + per-layer gauss arrays gauss[l*E + p] (contiguous per layer)
__global__ void fill_kernel(const int* __restrict__ src, const int* __restrict__ dst,
                            const float* __restrict__ pseudo, int* __restrict__ cursor,
                            int* __restrict__ csr_src, float2* __restrict__ gauss,
                            const float* __restrict__ mu1, const float* __restrict__ sigma1,
                            const float* __restrict__ mus, const float* __restrict__ sigmas) {
    int e = blockIdx.x * blockDim.x + threadIdx.x;
    if (e >= Ee) return;
    int p = atomicAdd(&cursor[dst[e]], 1);
    csr_src[p] = src[e];
    float2 ps = ((const float2*)pseudo)[e];
#pragma unroll
    for (int l = 0; l < Ll; ++l) {
        const float* mu = (l == 0) ? mu1 : mus + (l - 1) * 4;
        const float* sg = (l == 0) ? sigma1 : sigmas + (l - 1) * 4;
        float d00 = ps.x - mu[0], d01 = ps.y - mu[1];
        float d10 = ps.x - mu[2], d11 = ps.y - mu[3];
        float i00 = 1.f / (EPSg + sg[0] * sg[0]);
        float i01 = 1.f / (EPSg + sg[1] * sg[1]);
        float i10 = 1.f / (EPSg + sg[2] * sg[2]);
        float i11 = 1.f / (EPSg + sg[3] * sg[3]);
        float g0 = expf(-0.5f * (d00 * d00 * i00 + d01 * d01 * i01));
        float g1 = expf(-0.5f * (d10 * d10 * i10 + d11 * d11 * i11));
        gauss[(size_t)l * Ee + p] = make_float2(g0, g1);
    }
}

// ---- transform: hkp[n][h] = uint2{pack(b0k0,b1k0), pack(b0k1,b1k1)} ------
template<int F>
__global__ void transform_pack(const float* __restrict__ in, const float* __restrict__ g,
                               uint2* __restrict__ hkp) {
    int tid = threadIdx.x;
    int h = tid & 63;
    int r = tid >> 6;
    int n0 = blockIdx.x * 4;
    int n = n0 + r;
    __shared__ float s_in[4][2][F];
    for (int idx = tid; idx < 4 * 2 * F; idx += 256) {
        int rr = idx / (2 * F);
        int bb = (idx / F) & 1;
        int ff = idx % F;
        int gn = n0 + rr;
        s_in[rr][bb][ff] = (gn < Nn) ? in[((size_t)bb * Nn + gn) * F + ff] : 0.f;
    }
    __syncthreads();
    if (n >= Nn) return;
    float a00 = 0.f, a01 = 0.f, a10 = 0.f, a11 = 0.f;  // a{batch}{k}
#pragma unroll
    for (int f = 0; f < F; ++f) {
        float G0 = g[f * 128 + h];
        float G1 = g[f * 128 + 64 + h];
        float v0 = s_in[r][0][f];
        float v1 = s_in[r][1][f];
        a00 = fmaf(v0, G0, a00);
        a01 = fmaf(v0, G1, a01);
        a10 = fmaf(v1, G0, a10);
        a11 = fmaf(v1, G1, a11);
    }
    hkp[(size_t)n * 64 + h] = make_uint2(packbf(a00, a10), packbf(a01, a11));
}

// ---- gather + combine: one wave per node, 2-stage 8-edge pipeline --------

__device__ __forceinline__ void load_batch(int p0, int last,
    const int* __restrict__ csr_src, const float2* __restrict__ gauss,
    const uint2* __restrict__ hkp, int lane,
    uint2 (&U)[8], float2 (&G)[8]) {
#pragma unroll
    for (int j = 0; j < 8; ++j) {
        int p = p0 + j;
        int pc = p < last ? p : last;   // clamp to valid slot
        int srow = csr_src[pc];
        float2 g = gauss[pc];
        if (p > last) { g.x = 0.f; g.y = 0.f; }
        G[j] = g;
        U[j] = hkp[(size_t)srow * 64 + lane];
    }
}

template<int F>
__global__ __launch_bounds__(256, 4)
void gather_combine(const uint2* __restrict__ hkp, const int* __restrict__ offs,
                    const int* __restrict__ csr_src, const float2* __restrict__ gauss,
                    const float* __restrict__ prev, const float* __restrict__ root,
                    const float* __restrict__ bias, const float* __restrict__ fc_w,
                    int l, float* __restrict__ hout, float* __restrict__ node) {
    int tid = threadIdx.x;
    int lane = tid & 63;
    int n = blockIdx.x * 4 + (tid >> 6);
    if (n >= Nn) return;
    int s0 = offs[n], s1 = offs[n + 1];
    float acc0 = 0.f, acc1 = 0.f;
    if (s1 > s0) {
        int last = s1 - 1;
        uint2 Ua[8]; float2 Ga[8];
        load_batch(s0, last, csr_src, gauss, hkp, lane, Ua, Ga);
        for (int p0 = s0; p0 <= last; p0 += 8) {
            uint2 Ub[8]; float2 Gb[8];
            bool more = (p0 + 8) <= last;
            if (more) load_batch(p0 + 8, last, csr_src, gauss, hkp, lane, Ub, Gb);
#pragma unroll
            for (int j = 0; j < 8; ++j) {
                acc0 += Ga[j].x * uf(Ua[j].x << 16) + Ga[j].y * uf(Ua[j].y << 16);
                acc1 += Ga[j].x * uf(Ua[j].x & 0xFFFF0000u)
                      + Ga[j].y * uf(Ua[j].y & 0xFFFF0000u);
            }
            if (more) {
#pragma unroll
                for (int j = 0; j < 8; ++j) { Ua[j] = Ub[j]; Ga[j] = Gb[j]; }
            }
        }
    }
    float dg = (float)(s1 - s0);
    if (dg < 1.f) dg = 1.f;
    float inv = 1.f / dg;
    float bv = bias[lane];
    float fw = fc_w[lane * Ll + l];
#pragma unroll
    for (int b = 0; b < BSz; ++b) {
        size_t row = (size_t)b * Nn + n;
        float val = (b == 0 ? acc0 : acc1) * inv;
        float rsum = 0.f;
#pragma unroll
        for (int f = 0; f < F; ++f) rsum += prev[row * F + f] * root[f * 64 + lane];
        val += rsum + bv;
        val = val > 0.f ? val : expm1f(val);
        hout[row * 64 + lane] = val;
        float r = val * fw;
#pragma unroll
        for (int off = 32; off; off >>= 1) r += __shfl_down(r, off, 64);
        if (lane == 0) node[row] = (l == 0) ? r : node[row] + r;
    }
}

// ---- head ----------------------------------------------------------------

__global__ void lin1_kernel(const float* __restrict__ node, const float* __restrict__ w,
                            const float* __restrict__ fcb, float* __restrict__ h1acc) {
    int hfc = threadIdx.x;
    int n0 = blockIdx.x * 64;
    int nend = n0 + 64 < Nn ? n0 + 64 : Nn;
    float fb = fcb[0];
    float a0 = 0.f, a1 = 0.f;
    for (int n = n0; n < nend; ++n) {
        float wv = w[(size_t)n * HFCc + hfc];
        a0 += (node[n] + fb) * wv;
        a1 += (node[Nn + n] + fb) * wv;
    }
    atomicAdd(&h1acc[hfc], a0);
    atomicAdd(&h1acc[HFCc + hfc], a1);
}

__global__ void head_kernel(const float* __restrict__ h1acc, const float* __restrict__ l1b,
                            const float* __restrict__ w2, const float* __restrict__ b2,
                            float* __restrict__ out) {
    __shared__ float sh[HFCc];
    __shared__ float slog[NCc];
    __shared__ float s_lse;
    int tid = threadIdx.x;
    for (int b = 0; b < BSz; ++b) {
        float v = h1acc[b * HFCc + tid] + l1b[tid];
        v = v > 0.f ? v : expm1f(v);
        sh[tid] = v;
        __syncthreads();
        if (tid < NCc) {
            float s = b2[tid];
            for (int i = 0; i < HFCc; ++i) s += sh[i] * w2[i * NCc + tid];
            slog[tid] = s;
        }
        __syncthreads();
        if (tid == 0) {
            float m = slog[0];
            for (int c = 1; c < NCc; ++c) m = fmaxf(m, slog[c]);
            float se = 0.f;
            for (int c = 0; c < NCc; ++c) se += expf(slog[c] - m);
            s_lse = m + logf(se);
        }
        __syncthreads();
        if (tid < NCc) out[b * NCc + tid] = slog[tid] - s_lse;
        __syncthreads();
    }
}

extern "C" void kernel_launch(void* const* d_in, const int* in_sizes, int n_in,
                              void* d_out, int out_size, void* d_ws, size_t ws_size,
                              hipStream_t stream) {
    const float* x      = (const float*)d_in[0];
    const int*   ei     = (const int*)d_in[2];
    const float* pseudo = (const float*)d_in[3];
    const float* g1     = (const float*)d_in[4];
    const float* mu1    = (const float*)d_in[5];
    const float* sigma1 = (const float*)d_in[6];
    const float* root1  = (const float*)d_in[7];
    const float* b1     = (const float*)d_in[8];
    const float* gs     = (const float*)d_in[9];
    const float* mus    = (const float*)d_in[10];
    const float* sigmas = (const float*)d_in[11];
    const float* roots  = (const float*)d_in[12];
    const float* bs_p   = (const float*)d_in[13];
    const float* fc_w   = (const float*)d_in[14];
    const float* fc_b   = (const float*)d_in[15];
    const float* lin1_w = (const float*)d_in[16];
    const float* lin1_b = (const float*)d_in[17];
    const float* lin2_w = (const float*)d_in[18];
    const float* lin2_b = (const float*)d_in[19];
    float* out = (float*)d_out;

    const int* src = ei;
    const int* dst = ei + Ee;

    auto alignup = [](size_t v) { return (v + 255) & ~(size_t)255; };
    char* ws = (char*)d_ws;
    size_t off = 0;
    float*  node    = (float*)(ws + off);   off += alignup((size_t)BSz * Nn * 4);
    float*  h1acc   = (float*)(ws + off);   off += alignup((size_t)BSz * HFCc * 4);
    int*    offs    = (int*)(ws + off);     off += alignup((size_t)(Nn + 1) * 4);
    int*    cursor  = (int*)(ws + off);     off += alignup((size_t)Nn * 4);
    int*    loc     = (int*)(ws + off);     off += alignup((size_t)Nn * 4);
    int*    bsum    = (int*)(ws + off);     off += alignup((size_t)64 * 4);
    int*    csr_src = (int*)(ws + off);     off += alignup((size_t)Ee * 4);
    float2* gauss   = (float2*)(ws + off);  off += alignup((size_t)Ll * Ee * 8);
    uint2*  hkp     = (uint2*)(ws + off);   off += alignup((size_t)Nn * 64 * 8);
    float*  hA      = (float*)(ws + off);   off += alignup((size_t)BSz * Nn * 64 * 4);
    float*  hB      = (float*)(ws + off);   off += alignup((size_t)BSz * Nn * 64 * 4);
    (void)ws_size; (void)in_sizes; (void)n_in; (void)out_size;

    hipMemsetAsync(cursor, 0, (size_t)Nn * 4, stream);
    hipMemsetAsync(h1acc, 0, (size_t)BSz * HFCc * 4, stream);

    count_kernel<<<(Ee + 255) / 256, 256, 0, stream>>>(dst, cursor);
    scan_local<<<NBLK, 256, 0, stream>>>(cursor, loc, bsum);
    scan_tops<<<1, 64, 0, stream>>>(bsum);
    scan_fix<<<NBLK, 256, 0, stream>>>(loc, bsum, offs, cursor);
    fill_kernel<<<(Ee + 255) / 256, 256, 0, stream>>>(src, dst, pseudo, cursor, csr_src, gauss,
                                                      mu1, sigma1, mus, sigmas);

    const float* prev = x;
    float* hnxt = hA;
    float* hother = hB;
    int ngrid = (Nn + 3) / 4;
    for (int l = 0; l < Ll; ++l) {
        const float* g  = (l == 0) ? g1    : gs    + (size_t)(l - 1) * Hh * 128;
        const float* rt = (l == 0) ? root1 : roots + (size_t)(l - 1) * Hh * Hh;
        const float* bb = (l == 0) ? b1    : bs_p  + (size_t)(l - 1) * Hh;

        if (l == 0)
            transform_pack<F_INc><<<ngrid, 256, 0, stream>>>(prev, g, hkp);
        else
            transform_pack<Hh><<<ngrid, 256, 0, stream>>>(prev, g, hkp);

        if (l == 0)
            gather_combine<F_INc><<<ngrid, 256, 0, stream>>>(hkp, offs, csr_src,
                gauss + (size_t)l * Ee, prev, rt, bb, fc_w, l, hnxt, node);
        else
            gather_combine<Hh><<<ngrid, 256, 0, stream>>>(hkp, offs, csr_src,
                gauss + (size_t)l * Ee, prev, rt, bb, fc_w, l, hnxt, node);

        prev = hnxt;
        float* tmp = hnxt; hnxt = hother; hother = tmp;
    }

    lin1_kernel<<<(Nn + 63) / 64, 256, 0, stream>>>(node, lin1_w, fc_b, h1acc);
    head_kernel<<<1, HFCc, 0, stream>>>(h1acc, lin1_b, lin2_w, lin2_b, out);
}